// Round 5
// baseline (506.044 us; speedup 1.0000x reference)
//
#include <hip/hip_runtime.h>
#include <math.h>

#define Bsz 512
#define Nc  81
#define Rtot (Bsz*Nc)     /* 41472 rows */
#define DEG 20
#define Edim 16
#define HD  96
#define NITER 4

typedef __attribute__((ext_vector_type(8))) __bf16 bf16x8;
typedef __attribute__((ext_vector_type(4))) float f32x4;

__device__ __forceinline__ float sigf(float x){ return 1.0f/(1.0f+__expf(-x)); }
__device__ __forceinline__ float tanh_fast(float x){ return 2.0f/(1.0f+__expf(-2.0f*x)) - 1.0f; }

__device__ __forceinline__ unsigned short f2bf(float f){
    union{float f; unsigned u;} v; v.f=f;
    unsigned r = v.u + 0x7fff + ((v.u>>16)&1);
    return (unsigned short)(r>>16);
}
__device__ __forceinline__ float bf2f(unsigned short s){
    union{unsigned u; float f;} v; v.u=((unsigned)s)<<16; return v.f;
}
__device__ __forceinline__ bf16x8 pack8f(const float* x){
    bf16x8 r;
    #pragma unroll
    for (int j=0;j<8;j++) r[j]=(__bf16)x[j];
    return r;
}
__device__ __forceinline__ bf16x8 ldw(const __bf16* p){ return *(const bf16x8*)p; }

/* ---- swizzled LDS tile [16][96] fp32 (XOR 16B-chunk idx with row&7) ---- */
__device__ __forceinline__ int swz(int row, int col){
    return row*96 + ((((col>>2) ^ (row&7))<<2) | (col&3));
}
__device__ __forceinline__ void ldtr8(const float* tp, int row, int c, float* o){
    const int r96 = row*96, rho = row&7;
    const float4 a = *(const float4*)(tp + r96 + ((((c>>2)  ) ^ rho)<<2));
    const float4 b = *(const float4*)(tp + r96 + ((((c>>2)+1) ^ rho)<<2));
    o[0]=a.x;o[1]=a.y;o[2]=a.z;o[3]=a.w;o[4]=b.x;o[5]=b.y;o[6]=b.z;o[7]=b.w;
}
__device__ __forceinline__ bf16x8 packtr8(const float* tp, int row, int c){
    float t[8]; ldtr8(tp,row,c,t); return pack8f(t);
}

/* bf16 transposed-weight offsets inside ws (elements) */
#define OFF_FW1T 0          /* [192][96] */
#define OFF_FW2T 18432
#define OFF_FW3T 27648
#define OFF_GW1T 36864      /* [96][192] */
#define OFF_GW2T 55296
#define OFF_GW3T 64512
#define OFF_WIHT 73728      /* [384][96] */
#define OFF_WHHT 110592
#define OFF_RW1T 147456
#define OFF_RW2T 156672
#define OFF_RW3T 165888     /* [16][96] */
#define OFF_IW1T 167424     /* [96][32] (k repeated for hi/lo) */
#define OFF_IW2T 170496
#define OFF_IW3T 179712
#define WT_TOTAL 188928

/* ---------------- k_prep ---------------- */
__global__ __launch_bounds__(256) void k_prep(
    const float* __restrict__ fw1, const float* __restrict__ fw2, const float* __restrict__ fw3,
    const float* __restrict__ gw1, const float* __restrict__ gw2, const float* __restrict__ gw3,
    const float* __restrict__ wih, const float* __restrict__ whh,
    const float* __restrict__ rw1, const float* __restrict__ rw2, const float* __restrict__ rw3,
    const float* __restrict__ iw1, const float* __restrict__ iw2, const float* __restrict__ iw3,
    __bf16* __restrict__ wt)
{
    int i = blockIdx.x*256 + threadIdx.x;
    if (i >= WT_TOTAL) return;
    int j = i;
    if (j < 18432){ int n=j/96, k=j-n*96;
        wt[OFF_FW1T+j] = (__bf16)(n<96 ? fw1[k*96+n] : fw1[(96+k)*96+(n-96)]); return; }
    j -= 18432;
    if (j < 9216){ int n=j/96, k=j-n*96; wt[OFF_FW2T+j]=(__bf16)fw2[k*96+n]; return; }
    j -= 9216;
    if (j < 9216){ int n=j/96, k=j-n*96; wt[OFF_FW3T+j]=(__bf16)fw3[k*96+n]; return; }
    j -= 9216;
    if (j < 18432){ int n=j/192, k=j-n*192; wt[OFF_GW1T+j]=(__bf16)gw1[k*96+n]; return; }
    j -= 18432;
    if (j < 9216){ int n=j/96, k=j-n*96; wt[OFF_GW2T+j]=(__bf16)gw2[k*96+n]; return; }
    j -= 9216;
    if (j < 9216){ int n=j/96, k=j-n*96; wt[OFF_GW3T+j]=(__bf16)gw3[k*96+n]; return; }
    j -= 9216;
    if (j < 36864){ int n=j/96, k=j-n*96; wt[OFF_WIHT+j]=(__bf16)wih[k*384+n]; return; }
    j -= 36864;
    if (j < 36864){ int n=j/96, k=j-n*96; wt[OFF_WHHT+j]=(__bf16)whh[k*384+n]; return; }
    j -= 36864;
    if (j < 9216){ int n=j/96, k=j-n*96; wt[OFF_RW1T+j]=(__bf16)rw1[k*96+n]; return; }
    j -= 9216;
    if (j < 9216){ int n=j/96, k=j-n*96; wt[OFF_RW2T+j]=(__bf16)rw2[k*96+n]; return; }
    j -= 9216;
    if (j < 1536){ int n=j/96, k=j-n*96; wt[OFF_RW3T+j]=(__bf16)rw3[k*16+n]; return; }
    j -= 1536;
    if (j < 3072){ int n=j>>5, k=j&31; wt[OFF_IW1T+j]=(__bf16)iw1[(k&15)*96+n]; return; }
    j -= 3072;
    if (j < 9216){ int n=j/96, k=j-n*96; wt[OFF_IW2T+j]=(__bf16)iw2[k*96+n]; return; }
    j -= 9216;
    { int n=j/96, k=j-n*96; wt[OFF_IW3T+j]=(__bf16)iw3[k*96+n]; }
}

/* ---------------- k_embed2: embed + input MLP + initial A/Bm, all MFMA ----------------
   Layer 1 uses hi/lo split of the embedding values packed into one K=32 MFMA
   (hi in k=0..15, lo in k=16..31, weights repeated) -> fp32-accurate input. */
__global__ __launch_bounds__(64) void k_embed2(
    const int* __restrict__ grids, const float* __restrict__ embw,
    const __bf16* __restrict__ wt,
    const float* __restrict__ ib1, const float* __restrict__ ib2, const float* __restrict__ ib3,
    __bf16* __restrict__ X, __bf16* __restrict__ Ag, __bf16* __restrict__ Bmg)
{
    __shared__ float tp[16*96];
    const int lane = threadIdx.x & 63;
    const int row16 = lane&15, kgrp = lane>>4, ko = kgrp*8;
    const int rowA = blockIdx.x*16 + row16;
    const int rowO = blockIdx.x*16 + kgrp*4;

    const __bf16* iw1t = wt + OFF_IW1T;
    const __bf16* iw2t = wt + OFF_IW2T;
    const __bf16* iw3t = wt + OFF_IW3T;
    const __bf16* fw1t = wt + OFF_FW1T;

    /* embedding fragment: hi (kgrp 0,1) / lo (kgrp 2,3) */
    const int g = grids[rowA];
    const float* ew = embw + g*Edim + (kgrp&1)*8;
    bf16x8 ef;
    #pragma unroll
    for (int j=0;j<8;j++){
        float e = ew[j];
        if (kgrp < 2) ef[j] = (__bf16)e;
        else          ef[j] = (__bf16)(e - bf2f(f2bf(e)));
    }
    /* layer 1 (K=32 hi|lo) */
    #pragma unroll
    for (int nf=0;nf<6;nf++){
        f32x4 c={0.f,0.f,0.f,0.f};
        c=__builtin_amdgcn_mfma_f32_16x16x32_bf16(ef, ldw(iw1t+(size_t)(nf*16+row16)*32+ko), c,0,0,0);
        float b=ib1[nf*16+row16];
        #pragma unroll
        for (int q=0;q<4;q++) tp[swz(kgrp*4+q, nf*16+row16)]=fmaxf(c[q]+b,0.f);
    }
    __syncthreads();
    bf16x8 ta[3];
    #pragma unroll
    for (int kf=0;kf<3;kf++) ta[kf]=packtr8(tp,row16,kf*32+ko);
    __syncthreads();
    /* layer 2 */
    #pragma unroll
    for (int nf=0;nf<6;nf++){
        f32x4 c={0.f,0.f,0.f,0.f};
        #pragma unroll
        for (int kf=0;kf<3;kf++)
            c=__builtin_amdgcn_mfma_f32_16x16x32_bf16(ta[kf], ldw(iw2t+(size_t)(nf*16+row16)*HD+kf*32+ko), c,0,0,0);
        float b=ib2[nf*16+row16];
        #pragma unroll
        for (int q=0;q<4;q++) tp[swz(kgrp*4+q, nf*16+row16)]=fmaxf(c[q]+b,0.f);
    }
    __syncthreads();
    #pragma unroll
    for (int kf=0;kf<3;kf++) ta[kf]=packtr8(tp,row16,kf*32+ko);
    __syncthreads();
    /* layer 3 -> X (global bf16 + LDS fp32 for fragment rebuild) */
    #pragma unroll
    for (int nf=0;nf<6;nf++){
        f32x4 c={0.f,0.f,0.f,0.f};
        #pragma unroll
        for (int kf=0;kf<3;kf++)
            c=__builtin_amdgcn_mfma_f32_16x16x32_bf16(ta[kf], ldw(iw3t+(size_t)(nf*16+row16)*HD+kf*32+ko), c,0,0,0);
        float b=ib3[nf*16+row16];
        #pragma unroll
        for (int q=0;q<4;q++){
            float v=c[q]+b;
            X[(size_t)(rowO+q)*HD + nf*16+row16]=(__bf16)v;
            tp[swz(kgrp*4+q, nf*16+row16)]=v;
        }
    }
    __syncthreads();
    bf16x8 hf[3];
    #pragma unroll
    for (int kf=0;kf<3;kf++) hf[kf]=packtr8(tp,row16,kf*32+ko);
    /* initial [A|Bm] = h0 @ fw1 */
    #pragma unroll
    for (int nf=0;nf<12;nf++){
        f32x4 c={0.f,0.f,0.f,0.f};
        #pragma unroll
        for (int kf=0;kf<3;kf++)
            c=__builtin_amdgcn_mfma_f32_16x16x32_bf16(hf[kf], ldw(fw1t+(size_t)(nf*16+row16)*HD+kf*32+ko), c,0,0,0);
        __bf16* dst = (nf<6)? Ag : Bmg;
        int col = ((nf<6)? nf : nf-6)*16 + row16;
        #pragma unroll
        for (int q=0;q<4;q++) dst[(size_t)(rowO+q)*HD+col]=(__bf16)c[q];
    }
}

/* ---------------- k_edge: edge message MLP, prefetched gathers ---------------- */
__global__ __launch_bounds__(64) void k_edge(
    const __bf16* __restrict__ Ag, const __bf16* __restrict__ Bmg,
    const int* __restrict__ nbr,
    const float* __restrict__ fb1, const __bf16* __restrict__ fw2t,
    const float* __restrict__ fb2, const __bf16* __restrict__ fw3t,
    const float* __restrict__ fb3,
    __bf16* __restrict__ M)
{
    __shared__ float accs[16*96];
    const int lane = threadIdx.x & 63;
    const int row16 = lane&15, kgrp = lane>>4, ko = kgrp*8;
    const int rowA = blockIdx.x*16 + row16;
    const int iI = rowA % Nc;
    const __bf16* BmB = Bmg + (size_t)(rowA - iI)*HD + ko;

    bf16x8 w2f[3][6];
    #pragma unroll
    for (int kf=0; kf<3; kf++)
        #pragma unroll
        for (int nf=0; nf<6; nf++)
            w2f[kf][nf] = ldw(fw2t + (size_t)(nf*16+row16)*HD + kf*32+ko);

    float a[3][8];
    #pragma unroll
    for (int kf=0;kf<3;kf++){
        bf16x8 av = ldw(Ag + (size_t)rowA*HD + kf*32 + ko);
        #pragma unroll
        for (int j=0;j<8;j++) a[kf][j] = (float)av[j] + fb1[kf*32+ko+j];
    }
    float b2c[6], b3c[6];
    #pragma unroll
    for (int nf=0;nf<6;nf++){ b2c[nf]=fb2[nf*16+row16]; b3c[nf]=20.0f*fb3[nf*16+row16]; }

    f32x4 acc[6];
    #pragma unroll
    for (int nf=0;nf<6;nf++) acc[nf]=(f32x4){0.f,0.f,0.f,0.f};

    const int* nrow = nbr + iI*DEG;
    /* prime the gather pipeline */
    bf16x8 v0,v1,v2;
    {
        const __bf16* Vb = BmB + (size_t)nrow[0]*HD;
        v0=ldw(Vb); v1=ldw(Vb+32); v2=ldw(Vb+64);
    }
    #pragma unroll 2
    for (int d=0; d<DEG; d++){
        /* issue next gather before current compute */
        bf16x8 n0,n1,n2;
        {
            int dn = (d+1<DEG)? d+1 : 0;
            const __bf16* Vb = BmB + (size_t)nrow[dn]*HD;
            n0=ldw(Vb); n1=ldw(Vb+32); n2=ldw(Vb+64);
        }
        bf16x8 xf[3];
        {
            float t[8];
            #pragma unroll
            for (int jj=0;jj<8;jj++) t[jj]=fmaxf(a[0][jj]+(float)v0[jj],0.f);
            xf[0]=pack8f(t);
            #pragma unroll
            for (int jj=0;jj<8;jj++) t[jj]=fmaxf(a[1][jj]+(float)v1[jj],0.f);
            xf[1]=pack8f(t);
            #pragma unroll
            for (int jj=0;jj<8;jj++) t[jj]=fmaxf(a[2][jj]+(float)v2[jj],0.f);
            xf[2]=pack8f(t);
        }
        f32x4 c[6];
        #pragma unroll
        for (int nf=0;nf<6;nf++) c[nf]=(f32x4){0.f,0.f,0.f,0.f};
        #pragma unroll
        for (int kf=0;kf<3;kf++)
            #pragma unroll
            for (int nf=0;nf<6;nf++)
                c[nf]=__builtin_amdgcn_mfma_f32_16x16x32_bf16(xf[kf],w2f[kf][nf],c[nf],0,0,0);
        #pragma unroll
        for (int nf=0;nf<6;nf++)
            #pragma unroll
            for (int q2=0;q2<4;q2++)
                acc[nf][q2]+=fmaxf(c[nf][q2]+b2c[nf],0.f);
        v0=n0; v1=n1; v2=n2;
    }

    /* layer 3: in-wave transpose via swizzled LDS, hi/lo bf16 split */
    #pragma unroll
    for (int nf=0;nf<6;nf++)
        #pragma unroll
        for (int q2=0;q2<4;q2++)
            accs[swz(kgrp*4+q2, nf*16+row16)]=acc[nf][q2];
    __syncthreads();

    f32x4 c2[6];
    #pragma unroll
    for (int nf=0;nf<6;nf++) c2[nf]=(f32x4){0.f,0.f,0.f,0.f};
    #pragma unroll
    for (int kf=0;kf<3;kf++){
        float h[8]; ldtr8(accs, row16, kf*32+ko, h);
        bf16x8 hif, lof;
        #pragma unroll
        for (int j=0;j<8;j++){
            unsigned short hs=f2bf(h[j]);
            union{unsigned short s; __bf16 b;} u; u.s=hs;
            hif[j]=u.b; lof[j]=(__bf16)(h[j]-bf2f(hs));
        }
        #pragma unroll
        for (int nf=0;nf<6;nf++){
            bf16x8 w3f = ldw(fw3t + (size_t)(nf*16+row16)*HD + kf*32+ko);
            c2[nf]=__builtin_amdgcn_mfma_f32_16x16x32_bf16(hif,w3f,c2[nf],0,0,0);
            c2[nf]=__builtin_amdgcn_mfma_f32_16x16x32_bf16(lof,w3f,c2[nf],0,0,0);
        }
    }
    const int rowOut = blockIdx.x*16 + kgrp*4;
    #pragma unroll
    for (int nf=0;nf<6;nf++)
        #pragma unroll
        for (int q2=0;q2<4;q2++)
            M[(size_t)(rowOut+q2)*HD + nf*16+row16] = (__bf16)(c2[nf][q2]+b3c[nf]);
}

/* ---------------- k_fused: g-MLP + LSTM + readout + next-iter A/Bm (16 rows/wave) ---------------- */
__global__ __launch_bounds__(64) void k_fused(
    const __bf16* __restrict__ Xg, const __bf16* __restrict__ Mg,
    const __bf16* __restrict__ Hin, __bf16* __restrict__ Hout,
    const float* __restrict__ Cin, float* __restrict__ Cout,
    __bf16* __restrict__ Ag, __bf16* __restrict__ Bmg,
    const __bf16* __restrict__ wt,
    const float* __restrict__ gb1, const float* __restrict__ gb2, const float* __restrict__ gb3,
    const float* __restrict__ bih, const float* __restrict__ bhh,
    const float* __restrict__ rb1, const float* __restrict__ rb2, const float* __restrict__ rb3,
    float* __restrict__ out, int it, int wab)
{
    __shared__ float tp[16*96];
    const int lane = threadIdx.x & 63;
    const int row16 = lane&15, kgrp = lane>>4, ko = kgrp*8;
    const int rowA = blockIdx.x*16 + row16;
    const int rowO = blockIdx.x*16 + kgrp*4;

    const __bf16* fw1t = wt + OFF_FW1T;
    const __bf16* gw1t = wt + OFF_GW1T;
    const __bf16* gw2t = wt + OFF_GW2T;
    const __bf16* gw3t = wt + OFF_GW3T;
    const __bf16* wiht = wt + OFF_WIHT;
    const __bf16* whht = wt + OFF_WHHT;
    const __bf16* rw1t = wt + OFF_RW1T;
    const __bf16* rw2t = wt + OFF_RW2T;
    const __bf16* rw3t = wt + OFF_RW3T;

    /* ---- g layer 1: concat(X,M) @ gw1 ---- */
    bf16x8 xm[6];
    #pragma unroll
    for (int kf=0;kf<3;kf++){
        xm[kf]   = ldw(Xg + (size_t)rowA*HD + kf*32+ko);
        xm[3+kf] = ldw(Mg + (size_t)rowA*HD + kf*32+ko);
    }
    #pragma unroll
    for (int nf=0;nf<6;nf++){
        f32x4 c={0.f,0.f,0.f,0.f};
        #pragma unroll
        for (int kf=0;kf<6;kf++)
            c=__builtin_amdgcn_mfma_f32_16x16x32_bf16(xm[kf], ldw(gw1t+(size_t)(nf*16+row16)*192+kf*32+ko), c,0,0,0);
        float b=gb1[nf*16+row16];
        #pragma unroll
        for (int q=0;q<4;q++) tp[swz(kgrp*4+q, nf*16+row16)]=fmaxf(c[q]+b,0.f);
    }
    __syncthreads();
    bf16x8 ta[3];
    #pragma unroll
    for (int kf=0;kf<3;kf++) ta[kf]=packtr8(tp,row16,kf*32+ko);
    __syncthreads();
    /* ---- g layer 2 ---- */
    #pragma unroll
    for (int nf=0;nf<6;nf++){
        f32x4 c={0.f,0.f,0.f,0.f};
        #pragma unroll
        for (int kf=0;kf<3;kf++)
            c=__builtin_amdgcn_mfma_f32_16x16x32_bf16(ta[kf], ldw(gw2t+(size_t)(nf*16+row16)*HD+kf*32+ko), c,0,0,0);
        float b=gb2[nf*16+row16];
        #pragma unroll
        for (int q=0;q<4;q++) tp[swz(kgrp*4+q, nf*16+row16)]=fmaxf(c[q]+b,0.f);
    }
    __syncthreads();
    #pragma unroll
    for (int kf=0;kf<3;kf++) ta[kf]=packtr8(tp,row16,kf*32+ko);
    __syncthreads();
    /* ---- g layer 3 (linear) -> x_in ---- */
    #pragma unroll
    for (int nf=0;nf<6;nf++){
        f32x4 c={0.f,0.f,0.f,0.f};
        #pragma unroll
        for (int kf=0;kf<3;kf++)
            c=__builtin_amdgcn_mfma_f32_16x16x32_bf16(ta[kf], ldw(gw3t+(size_t)(nf*16+row16)*HD+kf*32+ko), c,0,0,0);
        float b=gb3[nf*16+row16];
        #pragma unroll
        for (int q=0;q<4;q++) tp[swz(kgrp*4+q, nf*16+row16)]=c[q]+b;
    }
    __syncthreads();
    bf16x8 xf[3];
    #pragma unroll
    for (int kf=0;kf<3;kf++) xf[kf]=packtr8(tp,row16,kf*32+ko);
    __syncthreads();

    /* ---- LSTM gates ---- */
    bf16x8 hfa[3];
    #pragma unroll
    for (int kf=0;kf<3;kf++) hfa[kf]=ldw(Hin + (size_t)rowA*HD + kf*32+ko);

    #pragma unroll 2
    for (int nf=0;nf<6;nf++){
        const int col = nf*16+row16;
        f32x4 g4[4];
        #pragma unroll
        for (int g=0;g<4;g++) g4[g]=(f32x4){0.f,0.f,0.f,0.f};
        #pragma unroll
        for (int g=0;g<4;g++){
            #pragma unroll
            for (int kf=0;kf<3;kf++){
                const int kk = kf*32+ko;
                g4[g]=__builtin_amdgcn_mfma_f32_16x16x32_bf16(xf[kf],  ldw(wiht+(size_t)(g*96+col)*HD+kk), g4[g],0,0,0);
                g4[g]=__builtin_amdgcn_mfma_f32_16x16x32_bf16(hfa[kf], ldw(whht+(size_t)(g*96+col)*HD+kk), g4[g],0,0,0);
            }
        }
        float bi=bih[    col]+bhh[    col];
        float bf=bih[ 96+col]+bhh[ 96+col];
        float bg=bih[192+col]+bhh[192+col];
        float bo=bih[288+col]+bhh[288+col];
        #pragma unroll
        for (int q=0;q<4;q++){
            size_t idx=(size_t)(rowO+q)*HD+col;
            float cold=Cin[idx];
            float iv=sigf(g4[0][q]+bi), fv=sigf(g4[1][q]+bf);
            float gv=tanh_fast(g4[2][q]+bg), ov=sigf(g4[3][q]+bo);
            float c2v=fv*cold+iv*gv;
            float h2v=ov*tanh_fast(c2v);
            Cout[idx]=c2v; Hout[idx]=(__bf16)h2v;
            tp[swz(kgrp*4+q,col)]=h2v;
        }
    }
    __syncthreads();

    /* ---- h2 fragments ---- */
    bf16x8 hf[3];
    #pragma unroll
    for (int kf=0;kf<3;kf++) hf[kf]=packtr8(tp,row16,kf*32+ko);
    __syncthreads();

    /* ---- next-iter [A|Bm] = h2 @ fw1 ---- */
    if (wab){
        #pragma unroll
        for (int nf=0;nf<12;nf++){
            f32x4 c={0.f,0.f,0.f,0.f};
            #pragma unroll
            for (int kf=0;kf<3;kf++)
                c=__builtin_amdgcn_mfma_f32_16x16x32_bf16(hf[kf], ldw(fw1t+(size_t)(nf*16+row16)*HD+kf*32+ko), c,0,0,0);
            __bf16* dst = (nf<6)? Ag : Bmg;
            int col = ((nf<6)? nf : nf-6)*16 + row16;
            #pragma unroll
            for (int q=0;q<4;q++) dst[(size_t)(rowO+q)*HD+col]=(__bf16)c[q];
        }
    }

    /* ---- readout layer 1 ---- */
    #pragma unroll
    for (int nf=0;nf<6;nf++){
        f32x4 c={0.f,0.f,0.f,0.f};
        #pragma unroll
        for (int kf=0;kf<3;kf++)
            c=__builtin_amdgcn_mfma_f32_16x16x32_bf16(hf[kf], ldw(rw1t+(size_t)(nf*16+row16)*HD+kf*32+ko), c,0,0,0);
        float b=rb1[nf*16+row16];
        #pragma unroll
        for (int q=0;q<4;q++) tp[swz(kgrp*4+q, nf*16+row16)]=fmaxf(c[q]+b,0.f);
    }
    __syncthreads();
    #pragma unroll
    for (int kf=0;kf<3;kf++) ta[kf]=packtr8(tp,row16,kf*32+ko);
    __syncthreads();
    /* ---- readout layer 2 ---- */
    #pragma unroll
    for (int nf=0;nf<6;nf++){
        f32x4 c={0.f,0.f,0.f,0.f};
        #pragma unroll
        for (int kf=0;kf<3;kf++)
            c=__builtin_amdgcn_mfma_f32_16x16x32_bf16(ta[kf], ldw(rw2t+(size_t)(nf*16+row16)*HD+kf*32+ko), c,0,0,0);
        float b=rb2[nf*16+row16];
        #pragma unroll
        for (int q=0;q<4;q++) tp[swz(kgrp*4+q, nf*16+row16)]=fmaxf(c[q]+b,0.f);
    }
    __syncthreads();
    #pragma unroll
    for (int kf=0;kf<3;kf++) ta[kf]=packtr8(tp,row16,kf*32+ko);
    /* ---- readout layer 3 -> out ---- */
    {
        f32x4 c={0.f,0.f,0.f,0.f};
        #pragma unroll
        for (int kf=0;kf<3;kf++)
            c=__builtin_amdgcn_mfma_f32_16x16x32_bf16(ta[kf], ldw(rw3t+(size_t)row16*HD+kf*32+ko), c,0,0,0);
        float b=rb3[row16];
        #pragma unroll
        for (int q=0;q<4;q++)
            out[((size_t)it*Rtot + rowO+q)*Edim + row16]=c[q]+b;
    }
}

extern "C" void kernel_launch(void* const* d_in, const int* in_sizes, int n_in,
                              void* d_out, int out_size, void* d_ws, size_t ws_size,
                              hipStream_t stream) {
    const int*   grids  = (const int*)  d_in[0];
    const int*   nbr    = (const int*)  d_in[1];
    const float* c0     = (const float*)d_in[3];
    const float* embw   = (const float*)d_in[4];
    const float* in_w1  = (const float*)d_in[5];
    const float* in_b1  = (const float*)d_in[6];
    const float* in_w2  = (const float*)d_in[7];
    const float* in_b2  = (const float*)d_in[8];
    const float* in_w3  = (const float*)d_in[9];
    const float* in_b3  = (const float*)d_in[10];
    const float* f_w1   = (const float*)d_in[11];
    const float* f_b1   = (const float*)d_in[12];
    const float* f_w2   = (const float*)d_in[13];
    const float* f_b2   = (const float*)d_in[14];
    const float* f_w3   = (const float*)d_in[15];
    const float* f_b3   = (const float*)d_in[16];
    const float* g_w1   = (const float*)d_in[17];
    const float* g_b1   = (const float*)d_in[18];
    const float* g_w2   = (const float*)d_in[19];
    const float* g_b2   = (const float*)d_in[20];
    const float* g_w3   = (const float*)d_in[21];
    const float* g_b3   = (const float*)d_in[22];
    const float* wih    = (const float*)d_in[23];
    const float* whh    = (const float*)d_in[24];
    const float* bih    = (const float*)d_in[25];
    const float* bhh    = (const float*)d_in[26];
    const float* r_w1   = (const float*)d_in[27];
    const float* r_b1   = (const float*)d_in[28];
    const float* r_w2   = (const float*)d_in[29];
    const float* r_b2   = (const float*)d_in[30];
    const float* r_w3   = (const float*)d_in[31];
    const float* r_b3   = (const float*)d_in[32];

    /* workspace layout */
    __bf16* Xb = (__bf16*)d_ws;                          /* Rtot*96 bf16 */
    __bf16* Hb = Xb + (size_t)Rtot*HD;
    float*  Cw = (float*)(Hb + (size_t)Rtot*HD);         /* Rtot*96 f32  */
    __bf16* Aa = (__bf16*)(Cw + (size_t)Rtot*HD);
    __bf16* Bm = Aa + (size_t)Rtot*HD;
    __bf16* Mm = Bm + (size_t)Rtot*HD;
    __bf16* wt = Mm + (size_t)Rtot*HD;
    float* out = (float*)d_out;

    const __bf16* fw2t = wt + OFF_FW2T;
    const __bf16* fw3t = wt + OFF_FW3T;

    hipLaunchKernelGGL(k_prep, dim3((WT_TOTAL+255)/256), dim3(256), 0, stream,
        f_w1, f_w2, f_w3, g_w1, g_w2, g_w3, wih, whh, r_w1, r_w2, r_w3,
        in_w1, in_w2, in_w3, wt);

    hipLaunchKernelGGL(k_embed2, dim3(Rtot/16), dim3(64), 0, stream,
        grids, embw, wt, in_b1, in_b2, in_b3, Xb, Aa, Bm);

    for (int it=0; it<NITER; ++it){
        hipLaunchKernelGGL(k_edge, dim3(Rtot/16), dim3(64), 0, stream,
            Aa, Bm, nbr, f_b1, fw2t, f_b2, fw3t, f_b3, Mm);
        hipLaunchKernelGGL(k_fused, dim3(Rtot/16), dim3(64), 0, stream,
            Xb, Mm,
            (it==0)? Xb : Hb, Hb,
            (it==0)? c0 : Cw, Cw,
            Aa, Bm, wt,
            g_b1, g_b2, g_b3, bih, bhh, r_b1, r_b2, r_b3,
            out, it, (it<NITER-1)?1:0);
    }
}

// Round 6
// 501.845 us; speedup vs baseline: 1.0084x; 1.0084x over previous
//
#include <hip/hip_runtime.h>
#include <math.h>

#define Bsz 512
#define Nc  81
#define Rtot (Bsz*Nc)     /* 41472 rows */
#define DEG 20
#define Edim 16
#define HD  96
#define NITER 4

typedef __attribute__((ext_vector_type(8))) __bf16 bf16x8;
typedef __attribute__((ext_vector_type(4))) float f32x4;

__device__ __forceinline__ float sigf(float x){ return 1.0f/(1.0f+__expf(-x)); }
__device__ __forceinline__ float tanh_fast(float x){ return 2.0f/(1.0f+__expf(-2.0f*x)) - 1.0f; }

__device__ __forceinline__ unsigned short f2bf(float f){
    union{float f; unsigned u;} v; v.f=f;
    unsigned r = v.u + 0x7fff + ((v.u>>16)&1);
    return (unsigned short)(r>>16);
}
__device__ __forceinline__ float bf2f(unsigned short s){
    union{unsigned u; float f;} v; v.u=((unsigned)s)<<16; return v.f;
}
__device__ __forceinline__ bf16x8 pack8f(const float* x){
    bf16x8 r;
    #pragma unroll
    for (int j=0;j<8;j++) r[j]=(__bf16)x[j];
    return r;
}
__device__ __forceinline__ bf16x8 ldw(const __bf16* p){ return *(const bf16x8*)p; }

/* ---- swizzled LDS tile [16][96] fp32 (XOR 16B-chunk idx with row&7) ---- */
__device__ __forceinline__ int swz(int row, int col){
    return row*96 + ((((col>>2) ^ (row&7))<<2) | (col&3));
}
__device__ __forceinline__ void ldtr8(const float* tp, int row, int c, float* o){
    const int r96 = row*96, rho = row&7;
    const float4 a = *(const float4*)(tp + r96 + ((((c>>2)  ) ^ rho)<<2));
    const float4 b = *(const float4*)(tp + r96 + ((((c>>2)+1) ^ rho)<<2));
    o[0]=a.x;o[1]=a.y;o[2]=a.z;o[3]=a.w;o[4]=b.x;o[5]=b.y;o[6]=b.z;o[7]=b.w;
}
__device__ __forceinline__ bf16x8 packtr8(const float* tp, int row, int c){
    float t[8]; ldtr8(tp,row,c,t); return pack8f(t);
}

/* bf16 transposed-weight offsets inside ws (elements) — legacy layout (edge/embed) */
#define OFF_FW1T 0          /* [192][96] */
#define OFF_FW2T 18432
#define OFF_FW3T 27648
#define OFF_GW1T 36864
#define OFF_GW2T 55296
#define OFF_GW3T 64512
#define OFF_WIHT 73728
#define OFF_WHHT 110592
#define OFF_RW1T 147456
#define OFF_RW2T 156672
#define OFF_RW3T 165888
#define OFF_IW1T 167424     /* [96][32] */
#define OFF_IW2T 170496
#define OFF_IW3T 179712
#define WT_TOTAL 188928

/* padded [rows][104] layouts for the LDS-staged fused kernel */
#define P_GW1A 0
#define P_GW1B 9984
#define P_GW2  19968
#define P_GW3  29952
#define P_WIH0 39936        /* 4 gates x 9984 */
#define P_WHH0 79872        /* 4 gates x 9984 */
#define P_FW1  119808       /* [192][104] */
#define P_RW1  139776
#define P_RW2  149760
#define P_RW3  159744       /* [16][104] */
#define P_TOTAL 161408

/* ---------------- k_prep (legacy layouts for edge/embed) ---------------- */
__global__ __launch_bounds__(256) void k_prep(
    const float* __restrict__ fw1, const float* __restrict__ fw2, const float* __restrict__ fw3,
    const float* __restrict__ gw1, const float* __restrict__ gw2, const float* __restrict__ gw3,
    const float* __restrict__ wih, const float* __restrict__ whh,
    const float* __restrict__ rw1, const float* __restrict__ rw2, const float* __restrict__ rw3,
    const float* __restrict__ iw1, const float* __restrict__ iw2, const float* __restrict__ iw3,
    __bf16* __restrict__ wt)
{
    int i = blockIdx.x*256 + threadIdx.x;
    if (i >= WT_TOTAL) return;
    int j = i;
    if (j < 18432){ int n=j/96, k=j-n*96;
        wt[OFF_FW1T+j] = (__bf16)(n<96 ? fw1[k*96+n] : fw1[(96+k)*96+(n-96)]); return; }
    j -= 18432;
    if (j < 9216){ int n=j/96, k=j-n*96; wt[OFF_FW2T+j]=(__bf16)fw2[k*96+n]; return; }
    j -= 9216;
    if (j < 9216){ int n=j/96, k=j-n*96; wt[OFF_FW3T+j]=(__bf16)fw3[k*96+n]; return; }
    j -= 9216;
    if (j < 18432){ int n=j/192, k=j-n*192; wt[OFF_GW1T+j]=(__bf16)gw1[k*96+n]; return; }
    j -= 18432;
    if (j < 9216){ int n=j/96, k=j-n*96; wt[OFF_GW2T+j]=(__bf16)gw2[k*96+n]; return; }
    j -= 9216;
    if (j < 9216){ int n=j/96, k=j-n*96; wt[OFF_GW3T+j]=(__bf16)gw3[k*96+n]; return; }
    j -= 9216;
    if (j < 36864){ int n=j/96, k=j-n*96; wt[OFF_WIHT+j]=(__bf16)wih[k*384+n]; return; }
    j -= 36864;
    if (j < 36864){ int n=j/96, k=j-n*96; wt[OFF_WHHT+j]=(__bf16)whh[k*384+n]; return; }
    j -= 36864;
    if (j < 9216){ int n=j/96, k=j-n*96; wt[OFF_RW1T+j]=(__bf16)rw1[k*96+n]; return; }
    j -= 9216;
    if (j < 9216){ int n=j/96, k=j-n*96; wt[OFF_RW2T+j]=(__bf16)rw2[k*96+n]; return; }
    j -= 9216;
    if (j < 1536){ int n=j/96, k=j-n*96; wt[OFF_RW3T+j]=(__bf16)rw3[k*16+n]; return; }
    j -= 1536;
    if (j < 3072){ int n=j>>5, k=j&31; wt[OFF_IW1T+j]=(__bf16)iw1[(k&15)*96+n]; return; }
    j -= 3072;
    if (j < 9216){ int n=j/96, k=j-n*96; wt[OFF_IW2T+j]=(__bf16)iw2[k*96+n]; return; }
    j -= 9216;
    { int n=j/96, k=j-n*96; wt[OFF_IW3T+j]=(__bf16)iw3[k*96+n]; }
}

/* ---------------- k_prep2: padded [*][104] layouts for k_fused256 ---------------- */
__global__ __launch_bounds__(256) void k_prep2(
    const float* __restrict__ gw1, const float* __restrict__ gw2, const float* __restrict__ gw3,
    const float* __restrict__ wih, const float* __restrict__ whh, const float* __restrict__ fw1,
    const float* __restrict__ rw1, const float* __restrict__ rw2, const float* __restrict__ rw3,
    __bf16* __restrict__ wp)
{
    int i = blockIdx.x*256 + threadIdx.x;
    if (i >= P_TOTAL) return;
    int j = i;
    if (j < 9984){ int o=j/104, k=j-o*104; wp[i]=(__bf16)((k<96)? gw1[k*96+o] : 0.f); return; }
    j -= 9984;
    if (j < 9984){ int o=j/104, k=j-o*104; wp[i]=(__bf16)((k<96)? gw1[(96+k)*96+o] : 0.f); return; }
    j -= 9984;
    if (j < 9984){ int o=j/104, k=j-o*104; wp[i]=(__bf16)((k<96)? gw2[k*96+o] : 0.f); return; }
    j -= 9984;
    if (j < 9984){ int o=j/104, k=j-o*104; wp[i]=(__bf16)((k<96)? gw3[k*96+o] : 0.f); return; }
    j -= 9984;
    if (j < 39936){ int g=j/9984, r=j-g*9984; int o=r/104, k=r-o*104;
        wp[i]=(__bf16)((k<96)? wih[k*384 + g*96 + o] : 0.f); return; }
    j -= 39936;
    if (j < 39936){ int g=j/9984, r=j-g*9984; int o=r/104, k=r-o*104;
        wp[i]=(__bf16)((k<96)? whh[k*384 + g*96 + o] : 0.f); return; }
    j -= 39936;
    if (j < 19968){ int o=j/104, k=j-o*104;
        wp[i]=(__bf16)((k>=96)? 0.f : (o<96 ? fw1[k*96+o] : fw1[(96+k)*96+(o-96)])); return; }
    j -= 19968;
    if (j < 9984){ int o=j/104, k=j-o*104; wp[i]=(__bf16)((k<96)? rw1[k*96+o]:0.f); return; }
    j -= 9984;
    if (j < 9984){ int o=j/104, k=j-o*104; wp[i]=(__bf16)((k<96)? rw2[k*96+o]:0.f); return; }
    j -= 9984;
    { int o=j/104, k=j-o*104; wp[i]=(__bf16)((k<96)? rw3[k*16+o]:0.f); }
}

/* ---------------- k_embed2: embed + input MLP + initial A/Bm (unchanged) ---------------- */
__global__ __launch_bounds__(64) void k_embed2(
    const int* __restrict__ grids, const float* __restrict__ embw,
    const __bf16* __restrict__ wt,
    const float* __restrict__ ib1, const float* __restrict__ ib2, const float* __restrict__ ib3,
    __bf16* __restrict__ X, __bf16* __restrict__ Ag, __bf16* __restrict__ Bmg)
{
    __shared__ float tp[16*96];
    const int lane = threadIdx.x & 63;
    const int row16 = lane&15, kgrp = lane>>4, ko = kgrp*8;
    const int rowA = blockIdx.x*16 + row16;
    const int rowO = blockIdx.x*16 + kgrp*4;

    const __bf16* iw1t = wt + OFF_IW1T;
    const __bf16* iw2t = wt + OFF_IW2T;
    const __bf16* iw3t = wt + OFF_IW3T;
    const __bf16* fw1t = wt + OFF_FW1T;

    const int g = grids[rowA];
    const float* ew = embw + g*Edim + (kgrp&1)*8;
    bf16x8 ef;
    #pragma unroll
    for (int j=0;j<8;j++){
        float e = ew[j];
        if (kgrp < 2) ef[j] = (__bf16)e;
        else          ef[j] = (__bf16)(e - bf2f(f2bf(e)));
    }
    #pragma unroll
    for (int nf=0;nf<6;nf++){
        f32x4 c={0.f,0.f,0.f,0.f};
        c=__builtin_amdgcn_mfma_f32_16x16x32_bf16(ef, ldw(iw1t+(size_t)(nf*16+row16)*32+ko), c,0,0,0);
        float b=ib1[nf*16+row16];
        #pragma unroll
        for (int q=0;q<4;q++) tp[swz(kgrp*4+q, nf*16+row16)]=fmaxf(c[q]+b,0.f);
    }
    __syncthreads();
    bf16x8 ta[3];
    #pragma unroll
    for (int kf=0;kf<3;kf++) ta[kf]=packtr8(tp,row16,kf*32+ko);
    __syncthreads();
    #pragma unroll
    for (int nf=0;nf<6;nf++){
        f32x4 c={0.f,0.f,0.f,0.f};
        #pragma unroll
        for (int kf=0;kf<3;kf++)
            c=__builtin_amdgcn_mfma_f32_16x16x32_bf16(ta[kf], ldw(iw2t+(size_t)(nf*16+row16)*HD+kf*32+ko), c,0,0,0);
        float b=ib2[nf*16+row16];
        #pragma unroll
        for (int q=0;q<4;q++) tp[swz(kgrp*4+q, nf*16+row16)]=fmaxf(c[q]+b,0.f);
    }
    __syncthreads();
    #pragma unroll
    for (int kf=0;kf<3;kf++) ta[kf]=packtr8(tp,row16,kf*32+ko);
    __syncthreads();
    #pragma unroll
    for (int nf=0;nf<6;nf++){
        f32x4 c={0.f,0.f,0.f,0.f};
        #pragma unroll
        for (int kf=0;kf<3;kf++)
            c=__builtin_amdgcn_mfma_f32_16x16x32_bf16(ta[kf], ldw(iw3t+(size_t)(nf*16+row16)*HD+kf*32+ko), c,0,0,0);
        float b=ib3[nf*16+row16];
        #pragma unroll
        for (int q=0;q<4;q++){
            float v=c[q]+b;
            X[(size_t)(rowO+q)*HD + nf*16+row16]=(__bf16)v;
            tp[swz(kgrp*4+q, nf*16+row16)]=v;
        }
    }
    __syncthreads();
    bf16x8 hf[3];
    #pragma unroll
    for (int kf=0;kf<3;kf++) hf[kf]=packtr8(tp,row16,kf*32+ko);
    #pragma unroll
    for (int nf=0;nf<12;nf++){
        f32x4 c={0.f,0.f,0.f,0.f};
        #pragma unroll
        for (int kf=0;kf<3;kf++)
            c=__builtin_amdgcn_mfma_f32_16x16x32_bf16(hf[kf], ldw(fw1t+(size_t)(nf*16+row16)*HD+kf*32+ko), c,0,0,0);
        __bf16* dst = (nf<6)? Ag : Bmg;
        int col = ((nf<6)? nf : nf-6)*16 + row16;
        #pragma unroll
        for (int q=0;q<4;q++) dst[(size_t)(rowO+q)*HD+col]=(__bf16)c[q];
    }
}

/* ---------------- k_edge (unchanged from round 5) ---------------- */
__global__ __launch_bounds__(64) void k_edge(
    const __bf16* __restrict__ Ag, const __bf16* __restrict__ Bmg,
    const int* __restrict__ nbr,
    const float* __restrict__ fb1, const __bf16* __restrict__ fw2t,
    const float* __restrict__ fb2, const __bf16* __restrict__ fw3t,
    const float* __restrict__ fb3,
    __bf16* __restrict__ M)
{
    __shared__ float accs[16*96];
    const int lane = threadIdx.x & 63;
    const int row16 = lane&15, kgrp = lane>>4, ko = kgrp*8;
    const int rowA = blockIdx.x*16 + row16;
    const int iI = rowA % Nc;
    const __bf16* BmB = Bmg + (size_t)(rowA - iI)*HD + ko;

    bf16x8 w2f[3][6];
    #pragma unroll
    for (int kf=0; kf<3; kf++)
        #pragma unroll
        for (int nf=0; nf<6; nf++)
            w2f[kf][nf] = ldw(fw2t + (size_t)(nf*16+row16)*HD + kf*32+ko);

    float a[3][8];
    #pragma unroll
    for (int kf=0;kf<3;kf++){
        bf16x8 av = ldw(Ag + (size_t)rowA*HD + kf*32 + ko);
        #pragma unroll
        for (int j=0;j<8;j++) a[kf][j] = (float)av[j] + fb1[kf*32+ko+j];
    }
    float b2c[6], b3c[6];
    #pragma unroll
    for (int nf=0;nf<6;nf++){ b2c[nf]=fb2[nf*16+row16]; b3c[nf]=20.0f*fb3[nf*16+row16]; }

    f32x4 acc[6];
    #pragma unroll
    for (int nf=0;nf<6;nf++) acc[nf]=(f32x4){0.f,0.f,0.f,0.f};

    const int* nrow = nbr + iI*DEG;
    bf16x8 v0,v1,v2;
    {
        const __bf16* Vb = BmB + (size_t)nrow[0]*HD;
        v0=ldw(Vb); v1=ldw(Vb+32); v2=ldw(Vb+64);
    }
    #pragma unroll 2
    for (int d=0; d<DEG; d++){
        bf16x8 n0,n1,n2;
        {
            int dn = (d+1<DEG)? d+1 : 0;
            const __bf16* Vb = BmB + (size_t)nrow[dn]*HD;
            n0=ldw(Vb); n1=ldw(Vb+32); n2=ldw(Vb+64);
        }
        bf16x8 xf[3];
        {
            float t[8];
            #pragma unroll
            for (int jj=0;jj<8;jj++) t[jj]=fmaxf(a[0][jj]+(float)v0[jj],0.f);
            xf[0]=pack8f(t);
            #pragma unroll
            for (int jj=0;jj<8;jj++) t[jj]=fmaxf(a[1][jj]+(float)v1[jj],0.f);
            xf[1]=pack8f(t);
            #pragma unroll
            for (int jj=0;jj<8;jj++) t[jj]=fmaxf(a[2][jj]+(float)v2[jj],0.f);
            xf[2]=pack8f(t);
        }
        f32x4 c[6];
        #pragma unroll
        for (int nf=0;nf<6;nf++) c[nf]=(f32x4){0.f,0.f,0.f,0.f};
        #pragma unroll
        for (int kf=0;kf<3;kf++)
            #pragma unroll
            for (int nf=0;nf<6;nf++)
                c[nf]=__builtin_amdgcn_mfma_f32_16x16x32_bf16(xf[kf],w2f[kf][nf],c[nf],0,0,0);
        #pragma unroll
        for (int nf=0;nf<6;nf++)
            #pragma unroll
            for (int q2=0;q2<4;q2++)
                acc[nf][q2]+=fmaxf(c[nf][q2]+b2c[nf],0.f);
        v0=n0; v1=n1; v2=n2;
    }

    #pragma unroll
    for (int nf=0;nf<6;nf++)
        #pragma unroll
        for (int q2=0;q2<4;q2++)
            accs[swz(kgrp*4+q2, nf*16+row16)]=acc[nf][q2];
    __syncthreads();

    f32x4 c2[6];
    #pragma unroll
    for (int nf=0;nf<6;nf++) c2[nf]=(f32x4){0.f,0.f,0.f,0.f};
    #pragma unroll
    for (int kf=0;kf<3;kf++){
        float h[8]; ldtr8(accs, row16, kf*32+ko, h);
        bf16x8 hif, lof;
        #pragma unroll
        for (int j=0;j<8;j++){
            unsigned short hs=f2bf(h[j]);
            union{unsigned short s; __bf16 b;} u; u.s=hs;
            hif[j]=u.b; lof[j]=(__bf16)(h[j]-bf2f(hs));
        }
        #pragma unroll
        for (int nf=0;nf<6;nf++){
            bf16x8 w3f = ldw(fw3t + (size_t)(nf*16+row16)*HD + kf*32+ko);
            c2[nf]=__builtin_amdgcn_mfma_f32_16x16x32_bf16(hif,w3f,c2[nf],0,0,0);
            c2[nf]=__builtin_amdgcn_mfma_f32_16x16x32_bf16(lof,w3f,c2[nf],0,0,0);
        }
    }
    const int rowOut = blockIdx.x*16 + kgrp*4;
    #pragma unroll
    for (int nf=0;nf<6;nf++)
        #pragma unroll
        for (int q2=0;q2<4;q2++)
            M[(size_t)(rowOut+q2)*HD + nf*16+row16] = (__bf16)(c2[nf][q2]+b3c[nf]);
}

/* ---------------- k_fused256: LDS-staged weights, 4 waves x 16 rows ---------------- */
__device__ __forceinline__ void stageW(const __bf16* __restrict__ src, __bf16* dst, int nelem){
    const int4* s=(const int4*)src; int4* d=(int4*)dst;
    const int n = nelem>>3;
    for (int i=threadIdx.x; i<n; i+=256) d[i]=s[i];
}
__device__ __forceinline__ bf16x8 ldl(const __bf16* w, int row, int kk){
    return *(const bf16x8*)(w + row*104 + kk);
}

__global__ __launch_bounds__(256,2) void k_fused256(
    const __bf16* __restrict__ Xg, const __bf16* __restrict__ Mg,
    const __bf16* __restrict__ Hin, __bf16* __restrict__ Hout,
    const float* __restrict__ Cin, float* __restrict__ Cout,
    __bf16* __restrict__ Ag, __bf16* __restrict__ Bmg,
    const __bf16* __restrict__ wp,
    const float* __restrict__ gb1, const float* __restrict__ gb2, const float* __restrict__ gb3,
    const float* __restrict__ bih, const float* __restrict__ bhh,
    const float* __restrict__ rb1, const float* __restrict__ rb2, const float* __restrict__ rb3,
    float* __restrict__ out, int it, int wab)
{
    __shared__ __align__(16) __bf16 wl[19968];   /* 39936 B weight chunk buffer */
    __shared__ float tp4[4][16*96];              /* 24576 B per-wave transpose tiles */
    const int tid = threadIdx.x;
    const int wave = tid>>6, lane = tid&63;
    const int row16=lane&15, kgrp=lane>>4, ko=kgrp*8;
    const int rowA = blockIdx.x*64 + wave*16 + row16;
    const int rowO = blockIdx.x*64 + wave*16 + kgrp*4;
    float* tp = tp4[wave];

    /* prologue: row-fragment global loads */
    bf16x8 xm[3], mm[3], hfa[3];
    #pragma unroll
    for (int kf=0;kf<3;kf++){
        xm[kf]  = ldw(Xg  + (size_t)rowA*HD + kf*32+ko);
        mm[kf]  = ldw(Mg  + (size_t)rowA*HD + kf*32+ko);
        hfa[kf] = ldw(Hin + (size_t)rowA*HD + kf*32+ko);
    }

    f32x4 acc[6];

    /* ---- g layer 1a: X part ---- */
    stageW(wp+P_GW1A, wl, 9984); __syncthreads();
    #pragma unroll
    for (int nf=0;nf<6;nf++){
        f32x4 c={0.f,0.f,0.f,0.f};
        const int row=nf*16+row16;
        #pragma unroll
        for (int kf=0;kf<3;kf++) c=__builtin_amdgcn_mfma_f32_16x16x32_bf16(xm[kf], ldl(wl,row,kf*32+ko), c,0,0,0);
        acc[nf]=c;
    }
    __syncthreads(); stageW(wp+P_GW1B, wl, 9984); __syncthreads();
    /* ---- g layer 1b: M part, relu -> tp ---- */
    #pragma unroll
    for (int nf=0;nf<6;nf++){
        f32x4 c=acc[nf];
        const int row=nf*16+row16;
        #pragma unroll
        for (int kf=0;kf<3;kf++) c=__builtin_amdgcn_mfma_f32_16x16x32_bf16(mm[kf], ldl(wl,row,kf*32+ko), c,0,0,0);
        float b=gb1[row];
        #pragma unroll
        for (int q=0;q<4;q++) tp[swz(kgrp*4+q,row)]=fmaxf(c[q]+b,0.f);
    }
    __syncthreads();
    bf16x8 ta[3];
    #pragma unroll
    for (int kf=0;kf<3;kf++) ta[kf]=packtr8(tp,row16,kf*32+ko);
    stageW(wp+P_GW2, wl, 9984);
    __syncthreads();
    /* ---- g layer 2 ---- */
    #pragma unroll
    for (int nf=0;nf<6;nf++){
        f32x4 c={0.f,0.f,0.f,0.f};
        const int row=nf*16+row16;
        #pragma unroll
        for (int kf=0;kf<3;kf++) c=__builtin_amdgcn_mfma_f32_16x16x32_bf16(ta[kf], ldl(wl,row,kf*32+ko), c,0,0,0);
        float b=gb2[row];
        #pragma unroll
        for (int q=0;q<4;q++) tp[swz(kgrp*4+q,row)]=fmaxf(c[q]+b,0.f);
    }
    __syncthreads();
    #pragma unroll
    for (int kf=0;kf<3;kf++) ta[kf]=packtr8(tp,row16,kf*32+ko);
    stageW(wp+P_GW3, wl, 9984);
    __syncthreads();
    /* ---- g layer 3 (linear) -> x_in ---- */
    #pragma unroll
    for (int nf=0;nf<6;nf++){
        f32x4 c={0.f,0.f,0.f,0.f};
        const int row=nf*16+row16;
        #pragma unroll
        for (int kf=0;kf<3;kf++) c=__builtin_amdgcn_mfma_f32_16x16x32_bf16(ta[kf], ldl(wl,row,kf*32+ko), c,0,0,0);
        float b=gb3[row];
        #pragma unroll
        for (int q=0;q<4;q++) tp[swz(kgrp*4+q,row)]=c[q]+b;
    }
    __syncthreads();
    bf16x8 xf[3];
    #pragma unroll
    for (int kf=0;kf<3;kf++) xf[kf]=packtr8(tp,row16,kf*32+ko);
    /* ---- LSTM gates: order i, g, f, o with incremental state ---- */
    stageW(wp+P_WIH0+0*9984, wl, 9984); stageW(wp+P_WHH0+0*9984, wl+9984, 9984);
    __syncthreads();
    float st[6][4];   /* iv -> pg */
    float cold[6][4];
    #pragma unroll
    for (int nf=0;nf<6;nf++)
        #pragma unroll
        for (int q=0;q<4;q++) cold[nf][q]=Cin[(size_t)(rowO+q)*HD + nf*16+row16];
    #pragma unroll
    for (int nf=0;nf<6;nf++){
        f32x4 c={0.f,0.f,0.f,0.f};
        const int row=nf*16+row16;
        #pragma unroll
        for (int kf=0;kf<3;kf++){
            c=__builtin_amdgcn_mfma_f32_16x16x32_bf16(xf[kf],  ldl(wl,      row,kf*32+ko), c,0,0,0);
            c=__builtin_amdgcn_mfma_f32_16x16x32_bf16(hfa[kf], ldl(wl+9984, row,kf*32+ko), c,0,0,0);
        }
        float b=bih[row]+bhh[row];
        #pragma unroll
        for (int q=0;q<4;q++) st[nf][q]=sigf(c[q]+b);
    }
    __syncthreads();
    stageW(wp+P_WIH0+2*9984, wl, 9984); stageW(wp+P_WHH0+2*9984, wl+9984, 9984);
    __syncthreads();
    #pragma unroll
    for (int nf=0;nf<6;nf++){
        f32x4 c={0.f,0.f,0.f,0.f};
        const int row=nf*16+row16;
        #pragma unroll
        for (int kf=0;kf<3;kf++){
            c=__builtin_amdgcn_mfma_f32_16x16x32_bf16(xf[kf],  ldl(wl,      row,kf*32+ko), c,0,0,0);
            c=__builtin_amdgcn_mfma_f32_16x16x32_bf16(hfa[kf], ldl(wl+9984, row,kf*32+ko), c,0,0,0);
        }
        float b=bih[192+row]+bhh[192+row];
        #pragma unroll
        for (int q=0;q<4;q++) st[nf][q]=st[nf][q]*tanh_fast(c[q]+b);
    }
    __syncthreads();
    stageW(wp+P_WIH0+1*9984, wl, 9984); stageW(wp+P_WHH0+1*9984, wl+9984, 9984);
    __syncthreads();
    float cacc[6][4];
    #pragma unroll
    for (int nf=0;nf<6;nf++){
        f32x4 c={0.f,0.f,0.f,0.f};
        const int row=nf*16+row16;
        #pragma unroll
        for (int kf=0;kf<3;kf++){
            c=__builtin_amdgcn_mfma_f32_16x16x32_bf16(xf[kf],  ldl(wl,      row,kf*32+ko), c,0,0,0);
            c=__builtin_amdgcn_mfma_f32_16x16x32_bf16(hfa[kf], ldl(wl+9984, row,kf*32+ko), c,0,0,0);
        }
        float b=bih[96+row]+bhh[96+row];
        #pragma unroll
        for (int q=0;q<4;q++) cacc[nf][q]=sigf(c[q]+b)*cold[nf][q]+st[nf][q];
    }
    __syncthreads();
    stageW(wp+P_WIH0+3*9984, wl, 9984); stageW(wp+P_WHH0+3*9984, wl+9984, 9984);
    __syncthreads();
    #pragma unroll
    for (int nf=0;nf<6;nf++){
        f32x4 c={0.f,0.f,0.f,0.f};
        const int row=nf*16+row16;
        #pragma unroll
        for (int kf=0;kf<3;kf++){
            c=__builtin_amdgcn_mfma_f32_16x16x32_bf16(xf[kf],  ldl(wl,      row,kf*32+ko), c,0,0,0);
            c=__builtin_amdgcn_mfma_f32_16x16x32_bf16(hfa[kf], ldl(wl+9984, row,kf*32+ko), c,0,0,0);
        }
        float b=bih[288+row]+bhh[288+row];
        #pragma unroll
        for (int q=0;q<4;q++){
            size_t idx=(size_t)(rowO+q)*HD+row;
            float c2v=cacc[nf][q];
            float h2v=sigf(c[q]+b)*tanh_fast(c2v);
            Cout[idx]=c2v; Hout[idx]=(__bf16)h2v;
            tp[swz(kgrp*4+q,row)]=h2v;
        }
    }
    __syncthreads();
    bf16x8 hf[3];
    #pragma unroll
    for (int kf=0;kf<3;kf++) hf[kf]=packtr8(tp,row16,kf*32+ko);
    if (wab) stageW(wp+P_FW1, wl, 19968);
    __syncthreads();
    /* ---- next-iter [A|Bm] ---- */
    if (wab){
        #pragma unroll
        for (int nf=0;nf<12;nf++){
            f32x4 c={0.f,0.f,0.f,0.f};
            const int row=nf*16+row16;
            #pragma unroll
            for (int kf=0;kf<3;kf++) c=__builtin_amdgcn_mfma_f32_16x16x32_bf16(hf[kf], ldl(wl,row,kf*32+ko), c,0,0,0);
            __bf16* dst = (nf<6)? Ag : Bmg;
            int col = ((nf<6)? nf : nf-6)*16 + row16;
            #pragma unroll
            for (int q=0;q<4;q++) dst[(size_t)(rowO+q)*HD+col]=(__bf16)c[q];
        }
    }
    __syncthreads();
    stageW(wp+P_RW1, wl, 9984);
    __syncthreads();
    /* ---- readout layer 1 ---- */
    #pragma unroll
    for (int nf=0;nf<6;nf++){
        f32x4 c={0.f,0.f,0.f,0.f};
        const int row=nf*16+row16;
        #pragma unroll
        for (int kf=0;kf<3;kf++) c=__builtin_amdgcn_mfma_f32_16x16x32_bf16(hf[kf], ldl(wl,row,kf*32+ko), c,0,0,0);
        float b=rb1[row];
        #pragma unroll
        for (int q=0;q<4;q++) tp[swz(kgrp*4+q,row)]=fmaxf(c[q]+b,0.f);
    }
    __syncthreads();
    #pragma unroll
    for (int kf=0;kf<3;kf++) ta[kf]=packtr8(tp,row16,kf*32+ko);
    stageW(wp+P_RW2, wl, 9984);
    __syncthreads();
    /* ---- readout layer 2 ---- */
    #pragma unroll
    for (int nf=0;nf<6;nf++){
        f32x4 c={0.f,0.f,0.f,0.f};
        const int row=nf*16+row16;
        #pragma unroll
        for (int kf=0;kf<3;kf++) c=__builtin_amdgcn_mfma_f32_16x16x32_bf16(ta[kf], ldl(wl,row,kf*32+ko), c,0,0,0);
        float b=rb2[row];
        #pragma unroll
        for (int q=0;q<4;q++) tp[swz(kgrp*4+q,row)]=fmaxf(c[q]+b,0.f);
    }
    __syncthreads();
    #pragma unroll
    for (int kf=0;kf<3;kf++) ta[kf]=packtr8(tp,row16,kf*32+ko);
    stageW(wp+P_RW3, wl, 1664);
    __syncthreads();
    /* ---- readout layer 3 -> out ---- */
    {
        f32x4 c={0.f,0.f,0.f,0.f};
        #pragma unroll
        for (int kf=0;kf<3;kf++) c=__builtin_amdgcn_mfma_f32_16x16x32_bf16(ta[kf], ldl(wl,row16,kf*32+ko), c,0,0,0);
        float b=rb3[row16];
        #pragma unroll
        for (int q=0;q<4;q++)
            out[((size_t)it*Rtot + rowO+q)*Edim + row16]=c[q]+b;
    }
}

extern "C" void kernel_launch(void* const* d_in, const int* in_sizes, int n_in,
                              void* d_out, int out_size, void* d_ws, size_t ws_size,
                              hipStream_t stream) {
    const int*   grids  = (const int*)  d_in[0];
    const int*   nbr    = (const int*)  d_in[1];
    const float* c0     = (const float*)d_in[3];
    const float* embw   = (const float*)d_in[4];
    const float* in_w1  = (const float*)d_in[5];
    const float* in_b1  = (const float*)d_in[6];
    const float* in_w2  = (const float*)d_in[7];
    const float* in_b2  = (const float*)d_in[8];
    const float* in_w3  = (const float*)d_in[9];
    const float* in_b3  = (const float*)d_in[10];
    const float* f_w1   = (const float*)d_in[11];
    const float* f_b1   = (const float*)d_in[12];
    const float* f_w2   = (const float*)d_in[13];
    const float* f_b2   = (const float*)d_in[14];
    const float* f_w3   = (const float*)d_in[15];
    const float* f_b3   = (const float*)d_in[16];
    const float* g_w1   = (const float*)d_in[17];
    const float* g_b1   = (const float*)d_in[18];
    const float* g_w2   = (const float*)d_in[19];
    const float* g_b2   = (const float*)d_in[20];
    const float* g_w3   = (const float*)d_in[21];
    const float* g_b3   = (const float*)d_in[22];
    const float* wih    = (const float*)d_in[23];
    const float* whh    = (const float*)d_in[24];
    const float* bih    = (const float*)d_in[25];
    const float* bhh    = (const float*)d_in[26];
    const float* r_w1   = (const float*)d_in[27];
    const float* r_b1   = (const float*)d_in[28];
    const float* r_w2   = (const float*)d_in[29];
    const float* r_b2   = (const float*)d_in[30];
    const float* r_w3   = (const float*)d_in[31];
    const float* r_b3   = (const float*)d_in[32];

    /* workspace layout */
    __bf16* Xb = (__bf16*)d_ws;
    __bf16* Hb = Xb + (size_t)Rtot*HD;
    float*  Cw = (float*)(Hb + (size_t)Rtot*HD);
    __bf16* Aa = (__bf16*)(Cw + (size_t)Rtot*HD);
    __bf16* Bm = Aa + (size_t)Rtot*HD;
    __bf16* Mm = Bm + (size_t)Rtot*HD;
    __bf16* wt = Mm + (size_t)Rtot*HD;
    __bf16* wpad = wt + WT_TOTAL;
    float* out = (float*)d_out;

    const __bf16* fw2t = wt + OFF_FW2T;
    const __bf16* fw3t = wt + OFF_FW3T;

    hipLaunchKernelGGL(k_prep, dim3((WT_TOTAL+255)/256), dim3(256), 0, stream,
        f_w1, f_w2, f_w3, g_w1, g_w2, g_w3, wih, whh, r_w1, r_w2, r_w3,
        in_w1, in_w2, in_w3, wt);
    hipLaunchKernelGGL(k_prep2, dim3((P_TOTAL+255)/256), dim3(256), 0, stream,
        g_w1, g_w2, g_w3, wih, whh, f_w1, r_w1, r_w2, r_w3, wpad);

    hipLaunchKernelGGL(k_embed2, dim3(Rtot/16), dim3(64), 0, stream,
        grids, embw, wt, in_b1, in_b2, in_b3, Xb, Aa, Bm);

    for (int it=0; it<NITER; ++it){
        hipLaunchKernelGGL(k_edge, dim3(Rtot/16), dim3(64), 0, stream,
            Aa, Bm, nbr, f_b1, fw2t, f_b2, fw3t, f_b3, Mm);
        hipLaunchKernelGGL(k_fused256, dim3(Rtot/64), dim3(256), 0, stream,
            Xb, Mm,
            (it==0)? Xb : Hb, Hb,
            (it==0)? c0 : Cw, Cw,
            Aa, Bm, wpad,
            g_b1, g_b2, g_b3, bih, bhh, r_b1, r_b2, r_b3,
            out, it, (it<NITER-1)?1:0);
    }
}